// Round 9
// baseline (162.867 us; speedup 1.0000x reference)
//
#include <hip/hip_runtime.h>
#include <hip/hip_bf16.h>

#define CIN  128
#define FOUT 128
#define HID  32
#define NREP 8
#define CAPR 16
#define EPSV 1e-8f

typedef __attribute__((ext_vector_type(8))) short bf16x8;
typedef __attribute__((ext_vector_type(4))) float f32x4;

__device__ inline short f2bf(float x) {
    union { float f; unsigned u; } v; v.f = x;
    unsigned r = v.u + 0x7fffu + ((v.u >> 16) & 1u);
    return (short)(r >> 16);
}
__device__ inline float bfbits2f(unsigned b) {
    union { unsigned u; float f; } v; v.u = b << 16;
    return v.f;
}

// ---------------------------------------------------------------------------
// Prep: WcT/W1T bf16 transposes, padded verts [N][4], zero replicated cursors.
// ---------------------------------------------------------------------------
__global__ void prep_kernel(const float* __restrict__ Wc,
                            const float* __restrict__ W1,
                            const float* __restrict__ verts,
                            short* __restrict__ WcT,
                            short* __restrict__ W1T,
                            float* __restrict__ vertsP,
                            int* __restrict__ cur2,    // [N][NREP]
                            int N) {
    const int idx = blockIdx.x * 256 + threadIdx.x;
    if (idx < CIN * FOUT) {
        const int c = idx >> 7, k = idx & 127;
        WcT[c * CIN + k] = f2bf(Wc[k * FOUT + c]);
    }
    if (idx < HID * CIN) {
        const int c = idx >> 7, k = idx & 127;
        W1T[c * CIN + k] = f2bf(W1[k * HID + c]);
    }
    if (idx < N) {
        vertsP[idx * 4 + 0] = verts[idx * 3 + 0];
        vertsP[idx * 4 + 1] = verts[idx * 3 + 1];
        vertsP[idx * 4 + 2] = verts[idx * 3 + 2];
        vertsP[idx * 4 + 3] = 0.f;
        ((int4*)cur2)[idx * 2 + 0] = make_int4(0, 0, 0, 0);
        ((int4*)cur2)[idx * 2 + 1] = make_int4(0, 0, 0, 0);
    }
}

// ---------------------------------------------------------------------------
// Fused block-specialized kernel:
//   blocks with (bid & 3) == 0 : per-16-vertex-wave MFMA vertex pipeline
//   other blocks               : edge bucket-scatter into XCD-private
//                                replicated sub-buckets (rep = bid & 7,
//                                round-robin block->XCD => same-L2 lines)
// ---------------------------------------------------------------------------
__global__ __launch_bounds__(256) void fused_kernel(
    const float* __restrict__ feat,
    const short* __restrict__ WcT,    // [FOUT][CIN] bf16
    const short* __restrict__ W1T,    // [HID][CIN] bf16
    const float* __restrict__ b1,
    const float* __restrict__ W2,     // [HID][9]
    const float* __restrict__ b2,
    float* __restrict__ Gp,           // [N][8] packed symmetric
    unsigned short* __restrict__ xwb, // [N][FOUT] bf16 bits
    const int* __restrict__ edges,
    int* __restrict__ cur2,           // [N][NREP]
    int* __restrict__ dstR,           // [N][NREP][CAPR]
    int N, int E, int nScat) {
    __shared__ unsigned short xw_s[4][16][FOUT];
    __shared__ float h_lds[4][16][HID];
    __shared__ float M_lds[4][16][9];

    const int bid = blockIdx.x;

    if ((bid & 3) != 0) {
        // -------------------- scatter path --------------------
        const int ls  = bid - (bid >> 2) - 1;    // dense index over scatter blocks
        const int rep = bid & (NREP - 1);
        const int stride = nScat * 256;
        for (int e = ls * 256 + (int)threadIdx.x; e < E; e += stride) {
            const int s = edges[e];
            const int d = edges[E + e];
            const int rk = atomicAdd(&cur2[s * NREP + rep], 1);
            if (rk < CAPR) dstR[((size_t)s * NREP + rep) * CAPR + rk] = d;
        }
        return;
    }

    // -------------------- vertex path --------------------
    const int lv = bid >> 2;
    if (lv * 64 >= N) return;

    const int wid  = threadIdx.x >> 6;
    const int lane = threadIdx.x & 63;
    const int v0   = (lv * 4 + wid) * 16;
    const int r    = lane & 15;
    const int hi   = lane >> 4;
    const int vr   = min(v0 + r, N - 1);

    // A fragments: 4 k-tiles of 32
    bf16x8 a[4];
#pragma unroll
    for (int kt = 0; kt < 4; ++kt) {
        const float* src = feat + (size_t)vr * CIN + kt * 32 + hi * 8;
        const float4 f0 = ((const float4*)src)[0];
        const float4 f1 = ((const float4*)src)[1];
        bf16x8 t;
        t[0] = f2bf(f0.x); t[1] = f2bf(f0.y); t[2] = f2bf(f0.z); t[3] = f2bf(f0.w);
        t[4] = f2bf(f1.x); t[5] = f2bf(f1.y); t[6] = f2bf(f1.z); t[7] = f2bf(f1.w);
        a[kt] = t;
    }

    // xw: 8 column tiles of 16 -> stage in LDS
#pragma unroll
    for (int ct = 0; ct < 8; ++ct) {
        f32x4 acc = {0.f, 0.f, 0.f, 0.f};
#pragma unroll
        for (int kt = 0; kt < 4; ++kt) {
            const bf16x8 b = *((const bf16x8*)(WcT + (size_t)(ct * 16 + r) * CIN + kt * 32 + hi * 8));
            acc = __builtin_amdgcn_mfma_f32_16x16x32_bf16(a[kt], b, acc, 0, 0, 0);
        }
#pragma unroll
        for (int reg = 0; reg < 4; ++reg)
            xw_s[wid][hi * 4 + reg][ct * 16 + r] = (unsigned short)f2bf(acc[reg]);
    }

    // coalesced store: one 256B row per wave-wide dword store
#pragma unroll
    for (int row = 0; row < 16; ++row) {
        if (v0 + row < N) {
            const unsigned d = ((const unsigned*)xw_s[wid][row])[lane];
            ((unsigned*)(xwb + (size_t)(v0 + row) * FOUT))[lane] = d;
        }
    }

    // h: 2 column tiles of 16 over W1T
#pragma unroll
    for (int ct = 0; ct < 2; ++ct) {
        f32x4 acc = {0.f, 0.f, 0.f, 0.f};
#pragma unroll
        for (int kt = 0; kt < 4; ++kt) {
            const bf16x8 b = *((const bf16x8*)(W1T + (size_t)(ct * 16 + r) * CIN + kt * 32 + hi * 8));
            acc = __builtin_amdgcn_mfma_f32_16x16x32_bf16(a[kt], b, acc, 0, 0, 0);
        }
        const float bb = b1[ct * 16 + r];
#pragma unroll
        for (int reg = 0; reg < 4; ++reg)
            h_lds[wid][hi * 4 + reg][ct * 16 + r] = fmaxf(acc[reg] + bb, 0.f);
    }
    __syncthreads();

    // M = h @ W2 + b2
    for (int idx = lane; idx < 144; idx += 64) {
        const int v = idx / 9, t = idx - v * 9;
        float m = b2[t];
#pragma unroll
        for (int k = 0; k < HID; ++k)
            m = fmaf(h_lds[wid][v][k], W2[k * 9 + t], m);
        M_lds[wid][v][t] = m;
    }
    __syncthreads();

    // Packed symmetric G
    for (int idx = lane; idx < 96; idx += 64) {
        const int v = idx / 6, t = idx - v * 6;
        const int i = (t >= 3) + (t >= 5);
        const int j = t - (t >= 3) * 2 - (t >= 5);
        float g = 0.f;
#pragma unroll
        for (int k = 0; k < 3; ++k)
            g += M_lds[wid][v][k * 3 + i] * M_lds[wid][v][k * 3 + j];
        if (v0 + v < N) Gp[(size_t)(v0 + v) * 8 + t] = g;
    }
}

// ---------------------------------------------------------------------------
// Aggregation: one wave per vertex. Lanes are assigned (rep = lane>>3,
// slot = lane&7 [+8 on rare pass 2]); valid lanes compute one edge weight;
// ballot-compacted loop broadcasts (dst, w) and does coalesced xwb row fma.
// ---------------------------------------------------------------------------
__global__ __launch_bounds__(256) void agg_kernel(const int* __restrict__ cur2,
                                                  const int* __restrict__ dstR,
                                                  const float* __restrict__ vertsP,
                                                  const float* __restrict__ Gp,
                                                  const unsigned short* __restrict__ xwb,
                                                  const float* __restrict__ bias,
                                                  float* __restrict__ out,
                                                  int N) {
    const int wid  = threadIdx.x >> 6;
    const int lane = threadIdx.x & 63;
    const int v = blockIdx.x * 4 + wid;
    if (v >= N) return;

    const int myrep = lane >> 3;
    const int slot0 = lane & 7;
    const int dr = min(cur2[v * NREP + myrep], CAPR);

    const float4 vs = ((const float4*)vertsP)[v];
    const float4 ga = ((const float4*)(Gp + (size_t)v * 8))[0];
    const float2 gb = ((const float2*)(Gp + (size_t)v * 8 + 4))[0];

    float ax = 0.f, ay = 0.f, wsum = 0.f;

    const int npass = __any(dr > 8) ? 2 : 1;
    for (int pass = 0; pass < npass; ++pass) {
        const int slot = slot0 + (pass << 3);
        const bool valid = slot < dr;
        int dval = 0; float wval = 0.f;
        if (valid) {
            dval = dstR[((size_t)v * NREP + myrep) * CAPR + slot];
            const float4 vd = ((const float4*)vertsP)[dval];
            const float4 ha = ((const float4*)(Gp + (size_t)dval * 8))[0];
            const float2 hb = ((const float2*)(Gp + (size_t)dval * 8 + 4))[0];
            const float t0 = vd.x - vs.x, t1 = vd.y - vs.y, t2 = vd.z - vs.z;
            const float g00 = ga.x + ha.x, g01 = ga.y + ha.y, g02 = ga.z + ha.z;
            const float g11 = ga.w + ha.w, g12 = gb.x + hb.x, g22 = gb.y + hb.y;
            const float q = 0.5f * (g00 * t0 * t0 + g11 * t1 * t1 + g22 * t2 * t2
                          + 2.f * (g01 * t0 * t1 + g02 * t0 * t2 + g12 * t1 * t2));
            wval = __expf(-q);
        }

        unsigned long long mask = __ballot(valid);
        while (mask) {
            const int b0 = __builtin_ctzll(mask); mask &= mask - 1;
            int b1 = b0, b2 = b0, b3 = b0;
            bool h1 = false, h2 = false, h3 = false;
            if (mask) { b1 = __builtin_ctzll(mask); mask &= mask - 1; h1 = true; }
            if (mask) { b2 = __builtin_ctzll(mask); mask &= mask - 1; h2 = true; }
            if (mask) { b3 = __builtin_ctzll(mask); mask &= mask - 1; h3 = true; }

            const int e0 = __shfl(dval, b0, 64);
            const int e1 = __shfl(dval, b1, 64);
            const int e2 = __shfl(dval, b2, 64);
            const int e3 = __shfl(dval, b3, 64);
            const float w0 = __shfl(wval, b0, 64);
            float w1 = __shfl(wval, b1, 64); if (!h1) w1 = 0.f;
            float w2 = __shfl(wval, b2, 64); if (!h2) w2 = 0.f;
            float w3 = __shfl(wval, b3, 64); if (!h3) w3 = 0.f;

            const unsigned u0 = ((const unsigned*)(xwb + (size_t)e0 * FOUT))[lane];
            const unsigned u1 = ((const unsigned*)(xwb + (size_t)e1 * FOUT))[lane];
            const unsigned u2 = ((const unsigned*)(xwb + (size_t)e2 * FOUT))[lane];
            const unsigned u3 = ((const unsigned*)(xwb + (size_t)e3 * FOUT))[lane];

            ax = fmaf(w0, bfbits2f(u0 & 0xffffu), ax); ay = fmaf(w0, bfbits2f(u0 >> 16), ay);
            ax = fmaf(w1, bfbits2f(u1 & 0xffffu), ax); ay = fmaf(w1, bfbits2f(u1 >> 16), ay);
            ax = fmaf(w2, bfbits2f(u2 & 0xffffu), ax); ay = fmaf(w2, bfbits2f(u2 >> 16), ay);
            ax = fmaf(w3, bfbits2f(u3 & 0xffffu), ax); ay = fmaf(w3, bfbits2f(u3 >> 16), ay);
            wsum += (w0 + w1) + (w2 + w3);
        }
    }

    const float inv = 1.f / (wsum + EPSV);
    const float2 b = ((const float2*)bias)[lane];
    float2 o;
    o.x = ax * inv + b.x;
    o.y = ay * inv + b.y;
    ((float2*)(out + (size_t)v * FOUT))[lane] = o;
}

extern "C" void kernel_launch(void* const* d_in, const int* in_sizes, int n_in,
                              void* d_out, int out_size, void* d_ws, size_t ws_size,
                              hipStream_t stream) {
    const float* feat  = (const float*)d_in[0];
    const float* verts = (const float*)d_in[1];
    const int*   edges = (const int*)d_in[2];
    // d_in[3] = faces (unused)
    const float* W1    = (const float*)d_in[4];
    const float* b1    = (const float*)d_in[5];
    const float* W2    = (const float*)d_in[6];
    const float* b2    = (const float*)d_in[7];
    const float* Wc    = (const float*)d_in[8];
    const float* bias  = (const float*)d_in[9];

    const int N = in_sizes[0] / CIN;
    const int E = in_sizes[2] / 2;

    // workspace layout (256B-aligned chunks)
    char* p = (char*)d_ws;
    auto alloc = [&](size_t bytes) {
        char* r = p;
        p += (bytes + 255) & ~(size_t)255;
        return r;
    };
    short*          WcT    = (short*)alloc((size_t)CIN * FOUT * sizeof(short));
    short*          W1T    = (short*)alloc((size_t)HID * CIN * sizeof(short));
    unsigned short* xwb    = (unsigned short*)alloc((size_t)N * FOUT * sizeof(short));
    float*          Gp     = (float*)alloc((size_t)N * 8 * sizeof(float));
    float*          vertsP = (float*)alloc((size_t)N * 4 * sizeof(float));
    int*            dstR   = (int*)alloc((size_t)N * NREP * CAPR * sizeof(int));
    int*            cur2   = (int*)alloc((size_t)N * NREP * sizeof(int));
    float*          out    = (float*)d_out;

    const int prep_n = (N > CIN * FOUT) ? N : CIN * FOUT;
    prep_kernel<<<(prep_n + 255) / 256, 256, 0, stream>>>(Wc, W1, verts, WcT, W1T, vertsP, cur2, N);

    // fused grid: 1/4 vertex blocks, 3/4 scatter blocks
    const int nvb = (N + 63) / 64;            // vertex blocks needed
    int grid = 4 * nvb;
    if (grid < 4096) grid = 4096;
    grid = (grid + 3) & ~3;                   // multiple of 4
    const int nScat = grid - (grid >> 2);     // blocks with (bid&3)!=0

    fused_kernel<<<grid, 256, 0, stream>>>(feat, WcT, W1T, b1, W2, b2, Gp, xwb,
                                           edges, cur2, dstR, N, E, nScat);

    agg_kernel<<<(N + 3) / 4, 256, 0, stream>>>(cur2, dstR, vertsP, Gp, xwb, bias, out, N);
}

// Round 10
// 133.184 us; speedup vs baseline: 1.2229x; 1.2229x over previous
//
#include <hip/hip_runtime.h>
#include <hip/hip_bf16.h>

#define CIN  128
#define FOUT 128
#define HID  32
#define NREP 8
#define CAPR 16
#define EPSV 1e-8f

typedef __attribute__((ext_vector_type(8))) short bf16x8;
typedef __attribute__((ext_vector_type(4))) float f32x4;

__device__ inline short f2bf(float x) {
    union { float f; unsigned u; } v; v.f = x;
    unsigned r = v.u + 0x7fffu + ((v.u >> 16) & 1u);
    return (short)(r >> 16);
}
__device__ inline float bfbits2f(unsigned b) {
    union { unsigned u; float f; } v; v.u = b << 16;
    return v.f;
}

// ---------------------------------------------------------------------------
// Prep: WcT/W1T bf16 transposes, padded verts [N][4], zero replicated
// cursors cur2[NREP][N].
// ---------------------------------------------------------------------------
__global__ void prep_kernel(const float* __restrict__ Wc,
                            const float* __restrict__ W1,
                            const float* __restrict__ verts,
                            short* __restrict__ WcT,
                            short* __restrict__ W1T,
                            float* __restrict__ vertsP,
                            int* __restrict__ cur2,    // [NREP][N]
                            int N) {
    const int idx = blockIdx.x * 256 + threadIdx.x;
    if (idx < CIN * FOUT) {
        const int c = idx >> 7, k = idx & 127;
        WcT[c * CIN + k] = f2bf(Wc[k * FOUT + c]);
    }
    if (idx < HID * CIN) {
        const int c = idx >> 7, k = idx & 127;
        W1T[c * CIN + k] = f2bf(W1[k * HID + c]);
    }
    if (idx < N) {
        vertsP[idx * 4 + 0] = verts[idx * 3 + 0];
        vertsP[idx * 4 + 1] = verts[idx * 3 + 1];
        vertsP[idx * 4 + 2] = verts[idx * 3 + 2];
        vertsP[idx * 4 + 3] = 0.f;
#pragma unroll
        for (int rep = 0; rep < NREP; ++rep)
            cur2[rep * N + idx] = 0;
    }
}

// ---------------------------------------------------------------------------
// Per-16-vertex wave: MFMA xw = feat@Wc (bf16), h = relu(feat@W1+b1),
// M = h@W2+b2, packed symmetric G = M^T M (6 vals, stride 8).
// ---------------------------------------------------------------------------
__global__ __launch_bounds__(256) void vertex_mfma(
    const float* __restrict__ feat,
    const short* __restrict__ WcT,    // [FOUT][CIN] bf16
    const short* __restrict__ W1T,    // [HID][CIN] bf16
    const float* __restrict__ b1,
    const float* __restrict__ W2,     // [HID][9]
    const float* __restrict__ b2,
    float* __restrict__ Gp,           // [N][8] packed symmetric
    unsigned short* __restrict__ xwb, // [N][FOUT] bf16 bits
    int N) {
    __shared__ unsigned short xw_s[4][16][FOUT];
    __shared__ float h_lds[4][16][HID];
    __shared__ float M_lds[4][16][9];
    const int wid  = threadIdx.x >> 6;
    const int lane = threadIdx.x & 63;
    const int v0   = (blockIdx.x * 4 + wid) * 16;
    const int r    = lane & 15;
    const int hi   = lane >> 4;
    const int vr   = min(v0 + r, N - 1);

    // A fragments: 4 k-tiles of 32
    bf16x8 a[4];
#pragma unroll
    for (int kt = 0; kt < 4; ++kt) {
        const float* src = feat + (size_t)vr * CIN + kt * 32 + hi * 8;
        const float4 f0 = ((const float4*)src)[0];
        const float4 f1 = ((const float4*)src)[1];
        bf16x8 t;
        t[0] = f2bf(f0.x); t[1] = f2bf(f0.y); t[2] = f2bf(f0.z); t[3] = f2bf(f0.w);
        t[4] = f2bf(f1.x); t[5] = f2bf(f1.y); t[6] = f2bf(f1.z); t[7] = f2bf(f1.w);
        a[kt] = t;
    }

    // xw: 8 column tiles of 16 -> stage in LDS
#pragma unroll
    for (int ct = 0; ct < 8; ++ct) {
        f32x4 acc = {0.f, 0.f, 0.f, 0.f};
#pragma unroll
        for (int kt = 0; kt < 4; ++kt) {
            const bf16x8 b = *((const bf16x8*)(WcT + (size_t)(ct * 16 + r) * CIN + kt * 32 + hi * 8));
            acc = __builtin_amdgcn_mfma_f32_16x16x32_bf16(a[kt], b, acc, 0, 0, 0);
        }
#pragma unroll
        for (int reg = 0; reg < 4; ++reg)
            xw_s[wid][hi * 4 + reg][ct * 16 + r] = (unsigned short)f2bf(acc[reg]);
    }

    // coalesced store: one 256B row per wave-wide dword store
#pragma unroll
    for (int row = 0; row < 16; ++row) {
        if (v0 + row < N) {
            const unsigned d = ((const unsigned*)xw_s[wid][row])[lane];
            ((unsigned*)(xwb + (size_t)(v0 + row) * FOUT))[lane] = d;
        }
    }

    // h: 2 column tiles of 16 over W1T
#pragma unroll
    for (int ct = 0; ct < 2; ++ct) {
        f32x4 acc = {0.f, 0.f, 0.f, 0.f};
#pragma unroll
        for (int kt = 0; kt < 4; ++kt) {
            const bf16x8 b = *((const bf16x8*)(W1T + (size_t)(ct * 16 + r) * CIN + kt * 32 + hi * 8));
            acc = __builtin_amdgcn_mfma_f32_16x16x32_bf16(a[kt], b, acc, 0, 0, 0);
        }
        const float bb = b1[ct * 16 + r];
#pragma unroll
        for (int reg = 0; reg < 4; ++reg)
            h_lds[wid][hi * 4 + reg][ct * 16 + r] = fmaxf(acc[reg] + bb, 0.f);
    }
    __syncthreads();

    // M = h @ W2 + b2
    for (int idx = lane; idx < 144; idx += 64) {
        const int v = idx / 9, t = idx - v * 9;
        float m = b2[t];
#pragma unroll
        for (int k = 0; k < HID; ++k)
            m = fmaf(h_lds[wid][v][k], W2[k * 9 + t], m);
        M_lds[wid][v][t] = m;
    }
    __syncthreads();

    // Packed symmetric G
    for (int idx = lane; idx < 96; idx += 64) {
        const int v = idx / 6, t = idx - v * 6;
        const int i = (t >= 3) + (t >= 5);
        const int j = t - (t >= 3) * 2 - (t >= 5);
        float g = 0.f;
#pragma unroll
        for (int k = 0; k < 3; ++k)
            g += M_lds[wid][v][k * 3 + i] * M_lds[wid][v][k * 3 + j];
        if (v0 + v < N) Gp[(size_t)(v0 + v) * 8 + t] = g;
    }
}

// ---------------------------------------------------------------------------
// Dedicated bucket-scatter, XCD-private replicated sub-buckets.
// rep = blockIdx & 7: with round-robin block->XCD dispatch all writers of a
// rep slice share one L2; slice (3.2 MB buckets + 200 KB cursors) is
// L2-resident, so the random 4B stores coalesce in L2 and write back once.
// Minimal registers / no LDS -> max occupancy for latency hiding.
// ---------------------------------------------------------------------------
__global__ void scatter_kernel(const int* __restrict__ edges,
                               int* __restrict__ cur2,     // [NREP][N]
                               int* __restrict__ dstR,     // [NREP][N][CAPR]
                               int N, int E) {
    const int e = blockIdx.x * 256 + threadIdx.x;
    if (e >= E) return;
    const int rep = blockIdx.x & (NREP - 1);
    const int s = edges[e];
    const int d = edges[E + e];
    const int rk = atomicAdd(&cur2[rep * N + s], 1);
    if (rk < CAPR) dstR[((size_t)rep * N + s) * CAPR + rk] = d;
}

// ---------------------------------------------------------------------------
// Aggregation: one wave per vertex. Lane = (rep = lane>>3, slot = lane&7,
// +8 on rare pass 2); valid lanes compute one edge weight; ballot-compacted
// loop broadcasts (dst, w) and does coalesced xwb row fma.
// ---------------------------------------------------------------------------
__global__ __launch_bounds__(256) void agg_kernel(const int* __restrict__ cur2,
                                                  const int* __restrict__ dstR,
                                                  const float* __restrict__ vertsP,
                                                  const float* __restrict__ Gp,
                                                  const unsigned short* __restrict__ xwb,
                                                  const float* __restrict__ bias,
                                                  float* __restrict__ out,
                                                  int N) {
    const int wid  = threadIdx.x >> 6;
    const int lane = threadIdx.x & 63;
    const int v = blockIdx.x * 4 + wid;
    if (v >= N) return;

    const int myrep = lane >> 3;
    const int slot0 = lane & 7;
    const int dr = min(cur2[myrep * N + v], CAPR);

    const float4 vs = ((const float4*)vertsP)[v];
    const float4 ga = ((const float4*)(Gp + (size_t)v * 8))[0];
    const float2 gb = ((const float2*)(Gp + (size_t)v * 8 + 4))[0];

    float ax = 0.f, ay = 0.f, wsum = 0.f;

    const int npass = __any(dr > 8) ? 2 : 1;
    for (int pass = 0; pass < npass; ++pass) {
        const int slot = slot0 + (pass << 3);
        const bool valid = slot < dr;
        int dval = 0; float wval = 0.f;
        if (valid) {
            dval = dstR[((size_t)myrep * N + v) * CAPR + slot];
            const float4 vd = ((const float4*)vertsP)[dval];
            const float4 ha = ((const float4*)(Gp + (size_t)dval * 8))[0];
            const float2 hb = ((const float2*)(Gp + (size_t)dval * 8 + 4))[0];
            const float t0 = vd.x - vs.x, t1 = vd.y - vs.y, t2 = vd.z - vs.z;
            const float g00 = ga.x + ha.x, g01 = ga.y + ha.y, g02 = ga.z + ha.z;
            const float g11 = ga.w + ha.w, g12 = gb.x + hb.x, g22 = gb.y + hb.y;
            const float q = 0.5f * (g00 * t0 * t0 + g11 * t1 * t1 + g22 * t2 * t2
                          + 2.f * (g01 * t0 * t1 + g02 * t0 * t2 + g12 * t1 * t2));
            wval = __expf(-q);
        }

        unsigned long long mask = __ballot(valid);
        while (mask) {
            const int b0 = __builtin_ctzll(mask); mask &= mask - 1;
            int b1 = b0, b2 = b0, b3 = b0;
            bool h1 = false, h2 = false, h3 = false;
            if (mask) { b1 = __builtin_ctzll(mask); mask &= mask - 1; h1 = true; }
            if (mask) { b2 = __builtin_ctzll(mask); mask &= mask - 1; h2 = true; }
            if (mask) { b3 = __builtin_ctzll(mask); mask &= mask - 1; h3 = true; }

            const int e0 = __shfl(dval, b0, 64);
            const int e1 = __shfl(dval, b1, 64);
            const int e2 = __shfl(dval, b2, 64);
            const int e3 = __shfl(dval, b3, 64);
            const float w0 = __shfl(wval, b0, 64);
            float w1 = __shfl(wval, b1, 64); if (!h1) w1 = 0.f;
            float w2 = __shfl(wval, b2, 64); if (!h2) w2 = 0.f;
            float w3 = __shfl(wval, b3, 64); if (!h3) w3 = 0.f;

            const unsigned u0 = ((const unsigned*)(xwb + (size_t)e0 * FOUT))[lane];
            const unsigned u1 = ((const unsigned*)(xwb + (size_t)e1 * FOUT))[lane];
            const unsigned u2 = ((const unsigned*)(xwb + (size_t)e2 * FOUT))[lane];
            const unsigned u3 = ((const unsigned*)(xwb + (size_t)e3 * FOUT))[lane];

            ax = fmaf(w0, bfbits2f(u0 & 0xffffu), ax); ay = fmaf(w0, bfbits2f(u0 >> 16), ay);
            ax = fmaf(w1, bfbits2f(u1 & 0xffffu), ax); ay = fmaf(w1, bfbits2f(u1 >> 16), ay);
            ax = fmaf(w2, bfbits2f(u2 & 0xffffu), ax); ay = fmaf(w2, bfbits2f(u2 >> 16), ay);
            ax = fmaf(w3, bfbits2f(u3 & 0xffffu), ax); ay = fmaf(w3, bfbits2f(u3 >> 16), ay);
            wsum += (w0 + w1) + (w2 + w3);
        }
    }

    const float inv = 1.f / (wsum + EPSV);
    const float2 b = ((const float2*)bias)[lane];
    float2 o;
    o.x = ax * inv + b.x;
    o.y = ay * inv + b.y;
    ((float2*)(out + (size_t)v * FOUT))[lane] = o;
}

extern "C" void kernel_launch(void* const* d_in, const int* in_sizes, int n_in,
                              void* d_out, int out_size, void* d_ws, size_t ws_size,
                              hipStream_t stream) {
    const float* feat  = (const float*)d_in[0];
    const float* verts = (const float*)d_in[1];
    const int*   edges = (const int*)d_in[2];
    // d_in[3] = faces (unused)
    const float* W1    = (const float*)d_in[4];
    const float* b1    = (const float*)d_in[5];
    const float* W2    = (const float*)d_in[6];
    const float* b2    = (const float*)d_in[7];
    const float* Wc    = (const float*)d_in[8];
    const float* bias  = (const float*)d_in[9];

    const int N = in_sizes[0] / CIN;
    const int E = in_sizes[2] / 2;

    // workspace layout (256B-aligned chunks)
    char* p = (char*)d_ws;
    auto alloc = [&](size_t bytes) {
        char* r = p;
        p += (bytes + 255) & ~(size_t)255;
        return r;
    };
    short*          WcT    = (short*)alloc((size_t)CIN * FOUT * sizeof(short));
    short*          W1T    = (short*)alloc((size_t)HID * CIN * sizeof(short));
    unsigned short* xwb    = (unsigned short*)alloc((size_t)N * FOUT * sizeof(short));
    float*          Gp     = (float*)alloc((size_t)N * 8 * sizeof(float));
    float*          vertsP = (float*)alloc((size_t)N * 4 * sizeof(float));
    int*            dstR   = (int*)alloc((size_t)NREP * N * CAPR * sizeof(int));
    int*            cur2   = (int*)alloc((size_t)NREP * N * sizeof(int));
    float*          out    = (float*)d_out;

    const int prep_n = (N > CIN * FOUT) ? N : CIN * FOUT;
    prep_kernel<<<(prep_n + 255) / 256, 256, 0, stream>>>(Wc, W1, verts, WcT, W1T, vertsP, cur2, N);

    const int nwaves = (N + 15) / 16;
    vertex_mfma<<<(nwaves + 3) / 4, 256, 0, stream>>>(feat, WcT, W1T, b1, W2, b2, Gp, xwb, N);

    scatter_kernel<<<(E + 255) / 256, 256, 0, stream>>>(edges, cur2, dstR, N, E);

    agg_kernel<<<(N + 3) / 4, 256, 0, stream>>>(cur2, dstR, vertsP, Gp, xwb, bias, out, N);
}